// Round 6
// baseline (413.680 us; speedup 1.0000x reference)
//
#include <hip/hip_runtime.h>
#include <math.h>

#define N_NODES 100000
#define N_EDGES 6400000
#define F_IN 128
#define F_OUT 16
#define NB 391                 // ceil(100000/256) buckets of 256 target nodes
#define EPB 4000               // edges per partition block: 1600 * 4000 = 6.4M exactly
#define KPB 2                  // scatter blocks per bucket
#define ACCN (NB * 256 * F_OUT)  // padded per-partial acc elements (1,601,536)
#define FPSCALE 524288.0f      // 2^19 fixed-point scale for LDS int accumulation
#define FPINV   (1.0f / 524288.0f)

// -------- 1. global bucket histogram (LDS pre-aggregation) --------
__global__ void hist_kernel(const int* __restrict__ col, int* __restrict__ gbhist) {
    __shared__ int h[NB];
    const int tid = threadIdx.x;
    for (int i = tid; i < NB; i += 256) h[i] = 0;
    __syncthreads();
    const int stride = gridDim.x * 256;
    for (int e = blockIdx.x * 256 + tid; e < N_EDGES; e += stride)
        atomicAdd(&h[col[e] >> 8], 1);
    __syncthreads();
    for (int i = tid; i < NB; i += 256) if (h[i]) atomicAdd(&gbhist[i], h[i]);
}

// -------- 2. exclusive scan of 391 bucket counts (one block) --------
__global__ void scan_kernel(const int* __restrict__ gbhist, int* __restrict__ boffs,
                            int* __restrict__ gcursor) {
    __shared__ int lds[512];
    const int tid = threadIdx.x;
    int v = (tid < NB) ? gbhist[tid] : 0;
    lds[tid] = v; __syncthreads();
    for (int off = 1; off < 512; off <<= 1) {
        int t = (tid >= off) ? lds[tid - off] : 0; __syncthreads();
        lds[tid] += t; __syncthreads();
    }
    int excl = lds[tid] - v;
    if (tid < NB) { boffs[tid] = excl; gcursor[tid] = excl; }
    if (tid == NB) boffs[NB] = N_EDGES;
}

// -------- 3. partition edges into bucket-contiguous runs --------
// packed = (row << 8) | (col & 255): row < 2^17, local col < 2^8 -> fits 25 bits.
// 1600 blocks, 4x unrolled: 4 independent ds_add_rtn chains per thread in flight.
__global__ void part_kernel(const int* __restrict__ row, const int* __restrict__ col,
                            int* __restrict__ gcursor, unsigned int* __restrict__ packed) {
    __shared__ int hist[NB];
    __shared__ int base[NB];
    const int tid = threadIdx.x;
    const int e0 = blockIdx.x * EPB, e1 = e0 + EPB;
    for (int i = tid; i < NB; i += 256) hist[i] = 0;
    __syncthreads();
    int i = e0 + tid;
    for (; i + 768 < e1; i += 1024) {
        int c0 = col[i], c1 = col[i + 256], c2 = col[i + 512], c3 = col[i + 768];
        atomicAdd(&hist[c0 >> 8], 1);
        atomicAdd(&hist[c1 >> 8], 1);
        atomicAdd(&hist[c2 >> 8], 1);
        atomicAdd(&hist[c3 >> 8], 1);
    }
    for (; i < e1; i += 256) atomicAdd(&hist[col[i] >> 8], 1);
    __syncthreads();
    for (int b = tid; b < NB; b += 256)
        base[b] = hist[b] ? atomicAdd(&gcursor[b], hist[b]) : 0;
    __syncthreads();
    for (int j = tid; j < NB; j += 256) hist[j] = 0;
    __syncthreads();
    i = e0 + tid;
    for (; i + 768 < e1; i += 1024) {
        int c0 = col[i], c1 = col[i + 256], c2 = col[i + 512], c3 = col[i + 768];
        int r0 = row[i], r1 = row[i + 256], r2 = row[i + 512], r3 = row[i + 768];
        int b0 = c0 >> 8, b1 = c1 >> 8, b2 = c2 >> 8, b3 = c3 >> 8;
        int p0 = base[b0] + atomicAdd(&hist[b0], 1);
        int p1 = base[b1] + atomicAdd(&hist[b1], 1);
        int p2 = base[b2] + atomicAdd(&hist[b2], 1);
        int p3 = base[b3] + atomicAdd(&hist[b3], 1);
        packed[p0] = ((unsigned)r0 << 8) | (unsigned)(c0 & 255);
        packed[p1] = ((unsigned)r1 << 8) | (unsigned)(c1 & 255);
        packed[p2] = ((unsigned)r2 << 8) | (unsigned)(c2 & 255);
        packed[p3] = ((unsigned)r3 << 8) | (unsigned)(c3 & 255);
    }
    for (; i < e1; i += 256) {
        int c = col[i];
        int b = c >> 8;
        int p = base[b] + atomicAdd(&hist[b], 1);
        packed[p] = ((unsigned)row[i] << 8) | (unsigned)(c & 255);
    }
}

// -------- 4. per-bucket degree histogram -> dinv (no global atomics) --------
__global__ void deg_kernel(const unsigned int* __restrict__ packed,
                           const int* __restrict__ boffs, float* __restrict__ dinv) {
    __shared__ int dh[256];
    const int tid = threadIdx.x;
    dh[tid] = 0;
    __syncthreads();
    const int b = blockIdx.x;
    const int e = boffs[b + 1];
    for (int i = boffs[b] + tid; i < e; i += 256)
        atomicAdd(&dh[packed[i] & 255u], 1);
    __syncthreads();
    const int node = (b << 8) + tid;
    if (node < N_NODES) dinv[node] = rsqrtf((float)dh[tid] + 1.0f);  // +1 self loop
}

// -------- 5. g[n,f] = dinv[n] * sum_k x[n,k] * W[k,f]; also bf16 copy g16 --------
__global__ void gemm_kernel(const float* __restrict__ x, const float* __restrict__ W,
                            const float* __restrict__ dinv, float* __restrict__ g,
                            unsigned short* __restrict__ g16) {
    __shared__ float Ws[F_IN * F_OUT];        // 8 KB
    __shared__ float xs[16 * (F_IN + 1)];
    const int tid = threadIdx.x;
    const int n0 = blockIdx.x * 16;
    for (int i = tid; i < F_IN * F_OUT; i += 256) Ws[i] = W[i];
    const float* xbase = x + (size_t)n0 * F_IN;
    for (int i = tid; i < 16 * F_IN; i += 256) {
        int r = i >> 7, c = i & 127;
        xs[r * (F_IN + 1) + c] = xbase[i];
    }
    __syncthreads();
    const int node = tid >> 4, f = tid & 15;
    const float* xr = &xs[node * (F_IN + 1)];
    float acc = 0.f;
    #pragma unroll 8
    for (int k = 0; k < F_IN; k++) acc += xr[k] * Ws[k * 16 + f];
    const float val = acc * dinv[n0 + node];
    const int idx = n0 * 16 + tid;
    g[idx] = val;
    unsigned u = __float_as_uint(val);          // bf16 RNE round for the gather table
    u += 0x7FFFu + ((u >> 16) & 1u);
    g16[idx] = (unsigned short)(u >> 16);
}

// -------- 6. per-bucket scatter-reduce: bf16 gather (L2-resident 3.2 MB table),
//            LDS INT fixed-point atomic accumulate (native ds_add_u32),
//            KPB=2 half-bucket blocks for CU-fill, plain-store flush. --------
__global__ void __launch_bounds__(1024) scatter_kernel(
        const unsigned int* __restrict__ packed, const int* __restrict__ boffs,
        const unsigned short* __restrict__ g16, float* __restrict__ accp) {
    __shared__ int sacc[256 * F_OUT];   // 16 KB
    const int tid = threadIdx.x;
    for (int i = tid; i < 256 * F_OUT; i += 1024) sacc[i] = 0;
    __syncthreads();
    const int b = blockIdx.x, part = blockIdx.y;
    const int s = boffs[b], e = boffs[b + 1];
    const int chunk = (e - s + KPB - 1) / KPB;
    const int cs = s + part * chunk;
    const int ce = min(cs + chunk, e);
    const int f = tid & 15;
    const int eg = tid >> 4;              // 0..63: 64 edges per step
    int i = cs + eg;
    for (; i + 192 < ce; i += 256) {      // 4x unroll: 4 gathers in flight per lane
        unsigned p0 = packed[i];
        unsigned p1 = packed[i + 64];
        unsigned p2 = packed[i + 128];
        unsigned p3 = packed[i + 192];
        float v0 = __uint_as_float((unsigned)g16[(p0 >> 8) * 16 + f] << 16);
        float v1 = __uint_as_float((unsigned)g16[(p1 >> 8) * 16 + f] << 16);
        float v2 = __uint_as_float((unsigned)g16[(p2 >> 8) * 16 + f] << 16);
        float v3 = __uint_as_float((unsigned)g16[(p3 >> 8) * 16 + f] << 16);
        atomicAdd(&sacc[((p0 & 255u) << 4) + f], __float2int_rn(v0 * FPSCALE));
        atomicAdd(&sacc[((p1 & 255u) << 4) + f], __float2int_rn(v1 * FPSCALE));
        atomicAdd(&sacc[((p2 & 255u) << 4) + f], __float2int_rn(v2 * FPSCALE));
        atomicAdd(&sacc[((p3 & 255u) << 4) + f], __float2int_rn(v3 * FPSCALE));
    }
    for (; i < ce; i += 64) {
        unsigned p0 = packed[i];
        float v0 = __uint_as_float((unsigned)g16[(p0 >> 8) * 16 + f] << 16);
        atomicAdd(&sacc[((p0 & 255u) << 4) + f], __float2int_rn(v0 * FPSCALE));
    }
    __syncthreads();
    const int nbase = b << 8;
    float* dst = accp + (size_t)part * ACCN + ((size_t)nbase << 4);
    for (int j = tid; j < 256 * F_OUT; j += 1024)
        if (nbase + (j >> 4) < N_NODES) dst[j] = (float)sacc[j] * FPINV;
}

// -------- 7. out_n = tanh(dinv[n]*(acc(n)+g[n]) + b); mean over n --------
__global__ void finalize_kernel(const float* __restrict__ accp, const float* __restrict__ g,
                                const float* __restrict__ dinv, const float* __restrict__ b,
                                double* __restrict__ dsum) {
    __shared__ float s[4][16];
    const int tid = threadIdx.x;
    const int f = tid & 15;
    const float bf = b[f];
    float local = 0.f;
    for (int i = blockIdx.x * blockDim.x + tid; i < N_NODES * F_OUT;
         i += gridDim.x * blockDim.x) {
        const int n = i >> 4;
        float a = accp[i] + accp[ACCN + i] + g[i];
        local += tanhf(dinv[n] * a + bf);
    }
    local += __shfl_down(local, 32);
    local += __shfl_down(local, 16);
    const int lane = tid & 63, wave = tid >> 6;
    if (lane < 16) s[wave][lane] = local;
    __syncthreads();
    if (tid < 16) {
        float v = s[0][tid] + s[1][tid] + s[2][tid] + s[3][tid];
        atomicAdd(&dsum[tid], (double)v);
    }
}

__global__ void out_kernel(const double* __restrict__ dsum, float* __restrict__ out) {
    const int f = threadIdx.x;
    if (f < 16) out[f] = (float)(dsum[f] * (1.0 / (double)N_NODES));
}

extern "C" void kernel_launch(void* const* d_in, const int* in_sizes, int n_in,
                              void* d_out, int out_size, void* d_ws, size_t ws_size,
                              hipStream_t stream) {
    const float* x  = (const float*)d_in[0];
    const int*   ei = (const int*)d_in[1];
    const float* W  = (const float*)d_in[2];
    const float* b  = (const float*)d_in[3];
    float* out = (float*)d_out;

    const int* row = ei;             // edge_index[0] = source
    const int* col = ei + N_EDGES;   // edge_index[1] = target

    // workspace layout (~49 MB):
    char* p = (char*)d_ws;
    double*         dsum    = (double*)p;          p += 16 * 8;
    int*            gbhist  = (int*)p;             p += NB * 4;
    int*            gcursor = (int*)p;             p += NB * 4;
    int*            boffs   = (int*)p;             p += (NB + 1) * 4;
    float*          dinv    = (float*)p;           p += (size_t)N_NODES * 4;
    float*          g       = (float*)p;           p += (size_t)N_NODES * F_OUT * 4;
    unsigned short* g16     = (unsigned short*)p;  p += (size_t)N_NODES * F_OUT * 2;
    unsigned int*   packed  = (unsigned int*)p;    p += (size_t)N_EDGES * 4;
    float*          accp    = (float*)p;           // KPB * ACCN floats (12.8 MB)

    // zero dsum + gbhist (contiguous)
    hipMemsetAsync(dsum, 0, 16 * 8 + NB * 4, stream);

    hist_kernel    <<<800, 256, 0, stream>>>(col, gbhist);
    scan_kernel    <<<1, 512, 0, stream>>>(gbhist, boffs, gcursor);
    part_kernel    <<<1600, 256, 0, stream>>>(row, col, gcursor, packed);
    deg_kernel     <<<NB, 256, 0, stream>>>(packed, boffs, dinv);
    gemm_kernel    <<<N_NODES / 16, 256, 0, stream>>>(x, W, dinv, g, g16);
    scatter_kernel <<<dim3(NB, KPB), 1024, 0, stream>>>(packed, boffs, g16, accp);
    finalize_kernel<<<640, 256, 0, stream>>>(accp, g, dinv, b, dsum);
    out_kernel     <<<1, 16, 0, stream>>>(dsum, out);
}

// Round 7
// 374.055 us; speedup vs baseline: 1.1059x; 1.1059x over previous
//
#include <hip/hip_runtime.h>
#include <math.h>

#define N_NODES 100000
#define N_EDGES 6400000
#define F_IN 128
#define F_OUT 16
#define NB 391                 // ceil(100000/256) buckets of 256 target nodes
#define NBLK 1600              // partition blocks (chunks)
#define EPB 4000               // edges per chunk: 1600 * 4000 = 6.4M exactly
#define LOCW 392               // loc row width (NB offsets + total)
#define KPB 2                  // scatter blocks per bucket
#define ACCN (NB * 256 * F_OUT)
#define FPSCALE 524288.0f      // 2^19 fixed-point scale for LDS int accumulation
#define FPINV   (1.0f / 524288.0f)

// -------- 1. block-local counting sort: each block sorts its 4000 edges by
//            bucket in LDS, flushes COALESCED to its own chunk + offset row.
//            No global atomics, no scattered global stores. --------
__global__ void __launch_bounds__(256) part2_kernel(const int* __restrict__ row,
        const int* __restrict__ col, unsigned int* __restrict__ packed,
        int* __restrict__ loc) {
    __shared__ int hist[NB];
    __shared__ int scanb[512];
    __shared__ int base[NB];
    __shared__ unsigned int tile[EPB];   // 16 KB
    const int t = threadIdx.x;
    const int k = blockIdx.x;
    const int e0 = k * EPB;
    int myc[16], myr[16];
    #pragma unroll
    for (int j = 0; j < 16; j++) {
        int idx = t + j * 256;
        if (idx < EPB) { myc[j] = col[e0 + idx]; myr[j] = row[e0 + idx]; }
        else { myc[j] = -1; myr[j] = 0; }
    }
    for (int i = t; i < NB; i += 256) hist[i] = 0;
    __syncthreads();
    #pragma unroll
    for (int j = 0; j < 16; j++)
        if (myc[j] >= 0) atomicAdd(&hist[myc[j] >> 8], 1);
    __syncthreads();
    // Hillis-Steele inclusive scan over 512 (NB padded), 2 slots/thread
    scanb[t] = (t < NB) ? hist[t] : 0;
    scanb[t + 256] = (t + 256 < NB) ? hist[t + 256] : 0;
    __syncthreads();
    for (int off = 1; off < 512; off <<= 1) {
        int a  = (t >= off) ? scanb[t - off] : 0;
        int a2 = scanb[t + 256 - off];          // t+256 >= off always (off<=256)
        __syncthreads();
        scanb[t] += a; scanb[t + 256] += a2;
        __syncthreads();
    }
    if (t < NB) base[t] = scanb[t] - hist[t];                  // exclusive
    if (t + 256 < NB) base[t + 256] = scanb[t + 256] - hist[t + 256];
    __syncthreads();
    // emit offset row; reset hist as cursor
    for (int bb = t; bb < NB; bb += 256) { loc[k * LOCW + bb] = base[bb]; hist[bb] = 0; }
    if (t == 0) loc[k * LOCW + NB] = EPB;
    __syncthreads();
    #pragma unroll
    for (int j = 0; j < 16; j++) {
        if (myc[j] >= 0) {
            int bb = myc[j] >> 8;
            int pos = base[bb] + atomicAdd(&hist[bb], 1);      // native ds_add_rtn
            tile[pos] = ((unsigned)myr[j] << 8) | (unsigned)(myc[j] & 255);
        }
    }
    __syncthreads();
    for (int i = t; i < EPB; i += 256) packed[e0 + i] = tile[i];  // coalesced flush
}

// -------- 2. transpose loc[NBLK][LOCW] -> locT[LOCW][NBLK] (coalesced reads later) --------
__global__ void transpose_kernel(const int* __restrict__ loc, int* __restrict__ locT) {
    __shared__ int tl[32][33];
    int b = blockIdx.x * 32 + threadIdx.x;
    int k = blockIdx.y * 32 + threadIdx.y;
    if (b < LOCW && k < NBLK) tl[threadIdx.y][threadIdx.x] = loc[k * LOCW + b];
    __syncthreads();
    int b2 = blockIdx.x * 32 + threadIdx.y;
    int k2 = blockIdx.y * 32 + threadIdx.x;
    if (b2 < LOCW && k2 < NBLK) locT[b2 * NBLK + k2] = tl[threadIdx.x][threadIdx.y];
}

// -------- 3. per-bucket degree histogram over segments -> dinv --------
__global__ void __launch_bounds__(1024) deg2_kernel(const unsigned int* __restrict__ packed,
        const int* __restrict__ locT, float* __restrict__ dinv) {
    __shared__ int dh[256];
    const int t = threadIdx.x;
    if (t < 256) dh[t] = 0;
    __syncthreads();
    const int b = blockIdx.x;
    const int w = t >> 6, l = t & 63;
    const int g = l >> 4, li = l & 15;
    const int spw = NBLK / 16;            // 100 segments per wave
    const int k0 = w * spw;
    const int* Ls = locT + (size_t)b * NBLK;
    const int* Le = locT + (size_t)(b + 1) * NBLK;
    for (int batch = 0; batch < spw; batch += 64) {
        int nseg = min(64, spw - batch);
        int kk = k0 + batch + l;
        int sv = (l < nseg) ? Ls[kk] : 0;
        int ev = (l < nseg) ? Le[kk] : 0;
        for (int s = 0; s < nseg; s += 4) {
            int ss = s + g;                       // 4 lane-groups, 4 segs in parallel
            int st = __shfl(sv, ss & 63);
            int en = __shfl(ev, ss & 63);
            if (ss >= nseg) en = st;
            const unsigned int* pp = packed + (size_t)(k0 + batch + ss) * EPB;
            for (int idx = st + li; idx < en; idx += 16)
                atomicAdd(&dh[pp[idx] & 255u], 1);
        }
    }
    __syncthreads();
    if (t < 256) {
        int node = (b << 8) + t;
        if (node < N_NODES) dinv[node] = rsqrtf((float)dh[t] + 1.0f);  // +1 self loop
    }
}

// -------- 4. g16[n,f] = bf16( dinv[n] * sum_k x[n,k] * W[k,f] ) --------
__global__ void gemm_kernel(const float* __restrict__ x, const float* __restrict__ W,
                            const float* __restrict__ dinv, unsigned short* __restrict__ g16) {
    __shared__ float Ws[F_IN * F_OUT];        // 8 KB
    __shared__ float xs[16 * (F_IN + 1)];
    const int tid = threadIdx.x;
    const int n0 = blockIdx.x * 16;
    for (int i = tid; i < F_IN * F_OUT; i += 256) Ws[i] = W[i];
    const float* xbase = x + (size_t)n0 * F_IN;
    for (int i = tid; i < 16 * F_IN; i += 256) {
        int r = i >> 7, c = i & 127;
        xs[r * (F_IN + 1) + c] = xbase[i];
    }
    __syncthreads();
    const int node = tid >> 4, f = tid & 15;
    const float* xr = &xs[node * (F_IN + 1)];
    float acc = 0.f;
    #pragma unroll 8
    for (int k = 0; k < F_IN; k++) acc += xr[k] * Ws[k * 16 + f];
    const float val = acc * dinv[n0 + node];
    unsigned u = __float_as_uint(val);          // bf16 RNE round
    u += 0x7FFFu + ((u >> 16) & 1u);
    g16[n0 * 16 + tid] = (unsigned short)(u >> 16);
}

// -------- 5. per-bucket scatter-reduce over segments: bf16 gather (L2-resident
//            3.2 MB table), native int LDS atomics, KPB=2 partials. --------
__global__ void __launch_bounds__(1024) scatter2_kernel(
        const unsigned int* __restrict__ packed, const int* __restrict__ locT,
        const unsigned short* __restrict__ g16, float* __restrict__ accp) {
    __shared__ int sacc[256 * F_OUT];   // 16 KB
    const int t = threadIdx.x;
    for (int i = t; i < 256 * F_OUT; i += 1024) sacc[i] = 0;
    __syncthreads();
    const int b = blockIdx.x, part = blockIdx.y;
    const int w = t >> 6, l = t & 63;
    const int es = l >> 4, f = l & 15;     // 4 edge-slots x 16 features
    const int spw = NBLK / (16 * KPB);     // 50 segments per wave
    const int k0 = part * (NBLK / KPB) + w * spw;
    const int* Ls = locT + (size_t)b * NBLK;
    const int* Le = locT + (size_t)(b + 1) * NBLK;
    int sv = (l < spw) ? Ls[k0 + l] : 0;
    int ev = (l < spw) ? Le[k0 + l] : 0;
    for (int s = 0; s < spw; s++) {
        int st = __shfl(sv, s);
        int en = __shfl(ev, s);
        const unsigned int* pp = packed + (size_t)(k0 + s) * EPB;
        for (int idx = st + es; idx < en; idx += 4) {
            unsigned pe = pp[idx];
            float v = __uint_as_float((unsigned)g16[(pe >> 8) * 16 + f] << 16);
            atomicAdd(&sacc[((pe & 255u) << 4) + f], __float2int_rn(v * FPSCALE));
        }
    }
    __syncthreads();
    const int nbase = b << 8;
    float* dst = accp + (size_t)part * ACCN + ((size_t)nbase << 4);
    for (int j = t; j < 256 * F_OUT; j += 1024)
        if (nbase + (j >> 4) < N_NODES) dst[j] = (float)sacc[j] * FPINV;
}

// -------- 6. out_n = tanh(dinv[n]*(acc(n)+g(n)) + b); mean over n --------
__global__ void finalize_kernel(const float* __restrict__ accp,
                                const unsigned short* __restrict__ g16,
                                const float* __restrict__ dinv, const float* __restrict__ b,
                                double* __restrict__ dsum) {
    __shared__ float s[4][16];
    const int tid = threadIdx.x;
    const int f = tid & 15;
    const float bf = b[f];
    float local = 0.f;
    for (int i = blockIdx.x * blockDim.x + tid; i < N_NODES * F_OUT;
         i += gridDim.x * blockDim.x) {
        const int n = i >> 4;
        float gv = __uint_as_float((unsigned)g16[i] << 16);
        float a = accp[i] + accp[ACCN + i] + gv;
        local += tanhf(dinv[n] * a + bf);
    }
    local += __shfl_down(local, 32);
    local += __shfl_down(local, 16);
    const int lane = tid & 63, wave = tid >> 6;
    if (lane < 16) s[wave][lane] = local;
    __syncthreads();
    if (tid < 16) {
        float v = s[0][tid] + s[1][tid] + s[2][tid] + s[3][tid];
        atomicAdd(&dsum[tid], (double)v);
    }
}

__global__ void out_kernel(const double* __restrict__ dsum, float* __restrict__ out) {
    const int f = threadIdx.x;
    if (f < 16) out[f] = (float)(dsum[f] * (1.0 / (double)N_NODES));
}

extern "C" void kernel_launch(void* const* d_in, const int* in_sizes, int n_in,
                              void* d_out, int out_size, void* d_ws, size_t ws_size,
                              hipStream_t stream) {
    const float* x  = (const float*)d_in[0];
    const int*   ei = (const int*)d_in[1];
    const float* W  = (const float*)d_in[2];
    const float* b  = (const float*)d_in[3];
    float* out = (float*)d_out;

    const int* row = ei;             // edge_index[0] = source
    const int* col = ei + N_EDGES;   // edge_index[1] = target

    // workspace layout (~47 MB):
    char* p = (char*)d_ws;
    double*         dsum   = (double*)p;          p += 16 * 8;
    int*            loc    = (int*)p;             p += (size_t)NBLK * LOCW * 4;  // 2.5 MB
    int*            locT   = (int*)p;             p += (size_t)LOCW * NBLK * 4;  // 2.5 MB
    float*          dinv   = (float*)p;           p += (size_t)N_NODES * 4;
    unsigned short* g16    = (unsigned short*)p;  p += (size_t)N_NODES * F_OUT * 2;
    unsigned int*   packed = (unsigned int*)p;    p += (size_t)N_EDGES * 4;      // 25.6 MB
    float*          accp   = (float*)p;           // KPB * ACCN floats (12.8 MB)

    hipMemsetAsync(dsum, 0, 16 * 8, stream);

    part2_kernel   <<<NBLK, 256, 0, stream>>>(row, col, packed, loc);
    transpose_kernel<<<dim3((LOCW + 31) / 32, NBLK / 32), dim3(32, 32), 0, stream>>>(loc, locT);
    deg2_kernel    <<<NB, 1024, 0, stream>>>(packed, locT, dinv);
    gemm_kernel    <<<N_NODES / 16, 256, 0, stream>>>(x, W, dinv, g16);
    scatter2_kernel<<<dim3(NB, KPB), 1024, 0, stream>>>(packed, locT, g16, accp);
    finalize_kernel<<<640, 256, 0, stream>>>(accp, g16, dinv, b, dsum);
    out_kernel     <<<1, 16, 0, stream>>>(dsum, out);
}

// Round 8
// 288.173 us; speedup vs baseline: 1.4355x; 1.2980x over previous
//
#include <hip/hip_runtime.h>
#include <math.h>

#define N_NODES 100000
#define N_EDGES 6400000
#define F_IN 128
#define F_OUT 16
#define NB 391                 // ceil(100000/256) buckets of 256 target nodes
#define NBLK 1600              // chunks
#define EPB 4000               // edges per chunk: 1600 * 4000 = 6.4M exactly
#define LOCW 392               // loc row width
#define KPB 3                  // scatter blocks per bucket (1173 blocks, ~4.6/CU, one round)
#define ACCN (NB * 256 * F_OUT)
#define QSCALE 1024.0f         // 2^10 fixed-point scale for the int16 gather table
#define QINV   (1.0f / 1024.0f)

// -------- 1. per-chunk per-bucket counts --------
__global__ void __launch_bounds__(256) count_kernel(const int* __restrict__ col,
                                                    int* __restrict__ loc) {
    __shared__ int hist[NB];
    const int t = threadIdx.x, k = blockIdx.x;
    for (int i = t; i < NB; i += 256) hist[i] = 0;
    __syncthreads();
    const int e0 = k * EPB;
    for (int i = t; i < EPB; i += 256) atomicAdd(&hist[col[e0 + i] >> 8], 1);
    __syncthreads();
    for (int b = t; b < NB; b += 256) loc[k * LOCW + b] = hist[b];
}

// -------- 2a. per-bucket exclusive prefix over chunks + bucket totals --------
__global__ void __launch_bounds__(256) desta_kernel(const int* __restrict__ loc,
        int* __restrict__ destT, int* __restrict__ total) {
    __shared__ int tsum[256];
    const int t = threadIdx.x, b = blockIdx.x;
    int v[7]; int s = 0;
    #pragma unroll
    for (int j = 0; j < 7; j++) {
        int k = t * 7 + j;
        v[j] = (k < NBLK) ? loc[k * LOCW + b] : 0;
        s += v[j];
    }
    tsum[t] = s;
    __syncthreads();
    for (int off = 1; off < 256; off <<= 1) {
        int a = (t >= off) ? tsum[t - off] : 0;
        __syncthreads();
        tsum[t] += a;
        __syncthreads();
    }
    int run = tsum[t] - s;   // exclusive prefix
    #pragma unroll
    for (int j = 0; j < 7; j++) {
        int k = t * 7 + j;
        if (k < NBLK) destT[(size_t)b * NBLK + k] = run;
        run += v[j];
    }
    if (t == 255) total[b] = tsum[255];
}

// -------- 2b. exclusive scan of bucket totals -> boffs --------
__global__ void destb_kernel(const int* __restrict__ total, int* __restrict__ boffs) {
    __shared__ int lds[512];
    const int t = threadIdx.x;
    int v = (t < NB) ? total[t] : 0;
    lds[t] = v; __syncthreads();
    for (int off = 1; off < 512; off <<= 1) {
        int a = (t >= off) ? lds[t - off] : 0; __syncthreads();
        lds[t] += a; __syncthreads();
    }
    if (t < NB) boffs[t] = lds[t] - v;
    if (t == NB) boffs[NB] = N_EDGES;
}

// -------- 3. place: LDS counting-sort each chunk, flush segments DIRECTLY to
//            bucket-contiguous global positions. --------
__global__ void __launch_bounds__(256) place_kernel(const int* __restrict__ row,
        const int* __restrict__ col, const int* __restrict__ destT,
        const int* __restrict__ boffs, unsigned int* __restrict__ packed) {
    __shared__ int hist[NB];
    __shared__ int scanb[512];
    __shared__ int base[NB];
    __shared__ int gadj[NB];
    __shared__ unsigned int tile[EPB];      // 16 KB
    __shared__ unsigned short tileb[EPB];   // 8 KB (bucket id per slot)
    const int t = threadIdx.x, k = blockIdx.x;
    const int e0 = k * EPB;
    int myc[16], myr[16];
    #pragma unroll
    for (int j = 0; j < 16; j++) {
        int idx = t + j * 256;
        if (idx < EPB) { myc[j] = col[e0 + idx]; myr[j] = row[e0 + idx]; }
        else { myc[j] = -1; myr[j] = 0; }
    }
    for (int i = t; i < NB; i += 256) hist[i] = 0;
    __syncthreads();
    #pragma unroll
    for (int j = 0; j < 16; j++)
        if (myc[j] >= 0) atomicAdd(&hist[myc[j] >> 8], 1);
    __syncthreads();
    scanb[t] = (t < NB) ? hist[t] : 0;
    scanb[t + 256] = (t + 256 < NB) ? hist[t + 256] : 0;
    __syncthreads();
    for (int off = 1; off < 512; off <<= 1) {
        int a  = (t >= off) ? scanb[t - off] : 0;
        int a2 = scanb[t + 256 - off];
        __syncthreads();
        scanb[t] += a; scanb[t + 256] += a2;
        __syncthreads();
    }
    if (t < NB) base[t] = scanb[t] - hist[t];
    if (t + 256 < NB) base[t + 256] = scanb[t + 256] - hist[t + 256];
    __syncthreads();
    for (int bb = t; bb < NB; bb += 256) {
        gadj[bb] = boffs[bb] + destT[(size_t)bb * NBLK + k] - base[bb];
        hist[bb] = 0;   // reuse as cursor
    }
    __syncthreads();
    #pragma unroll
    for (int j = 0; j < 16; j++) {
        if (myc[j] >= 0) {
            int bb = myc[j] >> 8;
            int pos = base[bb] + atomicAdd(&hist[bb], 1);     // native ds_add_rtn
            tile[pos] = ((unsigned)myr[j] << 8) | (unsigned)(myc[j] & 255);
            tileb[pos] = (unsigned short)bb;
        }
    }
    __syncthreads();
    for (int i = t; i < EPB; i += 256)
        packed[gadj[tileb[i]] + i] = tile[i];   // segment-contiguous global writes
}

// -------- 4. dense per-bucket degree -> dinv --------
__global__ void __launch_bounds__(256) deg_kernel(const unsigned int* __restrict__ packed,
        const int* __restrict__ boffs, float* __restrict__ dinv) {
    __shared__ int dh[256];
    const int t = threadIdx.x, b = blockIdx.x;
    dh[t] = 0;
    __syncthreads();
    const int e = boffs[b + 1];
    for (int i = boffs[b] + t; i < e; i += 256)
        atomicAdd(&dh[packed[i] & 255u], 1);
    __syncthreads();
    const int node = (b << 8) + t;
    if (node < N_NODES) dinv[node] = rsqrtf((float)dh[t] + 1.0f);   // +1 self loop
}

// -------- 5. gq[n,f] = int16( dinv[n] * (x@W)[n,f] * 2^10 ) --------
__global__ void gemm_kernel(const float* __restrict__ x, const float* __restrict__ W,
                            const float* __restrict__ dinv, short* __restrict__ gq) {
    __shared__ float Ws[F_IN * F_OUT];        // 8 KB
    __shared__ float xs[16 * (F_IN + 1)];
    const int tid = threadIdx.x;
    const int n0 = blockIdx.x * 16;
    for (int i = tid; i < F_IN * F_OUT; i += 256) Ws[i] = W[i];
    const float* xbase = x + (size_t)n0 * F_IN;
    for (int i = tid; i < 16 * F_IN; i += 256) {
        int r = i >> 7, c = i & 127;
        xs[r * (F_IN + 1) + c] = xbase[i];
    }
    __syncthreads();
    const int node = tid >> 4, f = tid & 15;
    const float* xr = &xs[node * (F_IN + 1)];
    float acc = 0.f;
    #pragma unroll 8
    for (int k = 0; k < F_IN; k++) acc += xr[k] * Ws[k * 16 + f];
    float v = acc * dinv[n0 + node] * QSCALE;
    v = fminf(fmaxf(v, -32000.f), 32000.f);
    gq[n0 * 16 + tid] = (short)__float2int_rn(v);
}

// -------- 6. dense scatter: int16 gather (3.2 MB L2-resident) -> ds_add directly.
//            KPB=3 slices, 256-thr blocks (1173 blocks, one resident round). --------
__global__ void __launch_bounds__(256) scatter_kernel(
        const unsigned int* __restrict__ packed, const int* __restrict__ boffs,
        const short* __restrict__ gq, int* __restrict__ accp) {
    __shared__ int sacc[256 * F_OUT];   // 16 KB
    const int t = threadIdx.x;
    for (int i = t; i < 256 * F_OUT; i += 256) sacc[i] = 0;
    __syncthreads();
    const int b = blockIdx.x, part = blockIdx.y;
    const int s = boffs[b], e = boffs[b + 1];
    const int chunk = (e - s + KPB - 1) / KPB;
    const int cs = s + part * chunk;
    const int ce = min(cs + chunk, e);
    const int f = t & 15, eg = t >> 4;    // 16 edges per step
    int i = cs + eg;
    for (; i + 48 < ce; i += 64) {        // 4x unroll: 4 gathers in flight
        unsigned p0 = packed[i];
        unsigned p1 = packed[i + 16];
        unsigned p2 = packed[i + 32];
        unsigned p3 = packed[i + 48];
        int v0 = gq[(p0 >> 8) * 16 + f];
        int v1 = gq[(p1 >> 8) * 16 + f];
        int v2 = gq[(p2 >> 8) * 16 + f];
        int v3 = gq[(p3 >> 8) * 16 + f];
        atomicAdd(&sacc[((p0 & 255u) << 4) + f], v0);
        atomicAdd(&sacc[((p1 & 255u) << 4) + f], v1);
        atomicAdd(&sacc[((p2 & 255u) << 4) + f], v2);
        atomicAdd(&sacc[((p3 & 255u) << 4) + f], v3);
    }
    for (; i < ce; i += 16) {
        unsigned p0 = packed[i];
        atomicAdd(&sacc[((p0 & 255u) << 4) + f], (int)gq[(p0 >> 8) * 16 + f]);
    }
    __syncthreads();
    const int nbase = b << 8;
    int* dst = accp + (size_t)part * ACCN + ((size_t)nbase << 4);
    for (int j = t; j < 256 * F_OUT; j += 256)
        if (nbase + (j >> 4) < N_NODES) dst[j] = sacc[j];
}

// -------- 7. out_n = tanh(dinv[n]*(acc+g) + b); mean over n --------
__global__ void finalize_kernel(const int* __restrict__ accp, const short* __restrict__ gq,
                                const float* __restrict__ dinv, const float* __restrict__ b,
                                double* __restrict__ dsum) {
    __shared__ float s[4][16];
    const int tid = threadIdx.x;
    const int f = tid & 15;
    const float bf = b[f];
    float local = 0.f;
    for (int i = blockIdx.x * blockDim.x + tid; i < N_NODES * F_OUT;
         i += gridDim.x * blockDim.x) {
        const int n = i >> 4;
        int ai = accp[i] + accp[ACCN + i] + accp[2 * ACCN + i] + (int)gq[i];
        local += tanhf(dinv[n] * ((float)ai * QINV) + bf);
    }
    local += __shfl_down(local, 32);
    local += __shfl_down(local, 16);
    const int lane = tid & 63, wave = tid >> 6;
    if (lane < 16) s[wave][lane] = local;
    __syncthreads();
    if (tid < 16) {
        float v = s[0][tid] + s[1][tid] + s[2][tid] + s[3][tid];
        atomicAdd(&dsum[tid], (double)v);
    }
}

__global__ void out_kernel(const double* __restrict__ dsum, float* __restrict__ out) {
    const int f = threadIdx.x;
    if (f < 16) out[f] = (float)(dsum[f] * (1.0 / (double)N_NODES));
}

extern "C" void kernel_launch(void* const* d_in, const int* in_sizes, int n_in,
                              void* d_out, int out_size, void* d_ws, size_t ws_size,
                              hipStream_t stream) {
    const float* x  = (const float*)d_in[0];
    const int*   ei = (const int*)d_in[1];
    const float* W  = (const float*)d_in[2];
    const float* b  = (const float*)d_in[3];
    float* out = (float*)d_out;

    const int* row = ei;             // edge_index[0] = source
    const int* col = ei + N_EDGES;   // edge_index[1] = target

    // workspace layout (~54 MB):
    char* p = (char*)d_ws;
    double*       dsum   = (double*)p;        p += 16 * 8;
    int*          loc    = (int*)p;           p += (size_t)NBLK * LOCW * 4;   // 2.5 MB
    int*          destT  = (int*)p;           p += (size_t)NB * NBLK * 4;     // 2.5 MB
    int*          total  = (int*)p;           p += NB * 4;
    int*          boffs  = (int*)p;           p += (NB + 1) * 4;
    float*        dinv   = (float*)p;         p += (size_t)N_NODES * 4;       // 0.4 MB
    short*        gq     = (short*)p;         p += (size_t)N_NODES * F_OUT * 2; // 3.2 MB
    unsigned int* packed = (unsigned int*)p;  p += (size_t)N_EDGES * 4;       // 25.6 MB
    int*          accp   = (int*)p;           // KPB * ACCN int32 (19.2 MB)

    hipMemsetAsync(dsum, 0, 16 * 8, stream);

    count_kernel   <<<NBLK, 256, 0, stream>>>(col, loc);
    desta_kernel   <<<NB, 256, 0, stream>>>(loc, destT, total);
    destb_kernel   <<<1, 512, 0, stream>>>(total, boffs);
    place_kernel   <<<NBLK, 256, 0, stream>>>(row, col, destT, boffs, packed);
    deg_kernel     <<<NB, 256, 0, stream>>>(packed, boffs, dinv);
    gemm_kernel    <<<N_NODES / 16, 256, 0, stream>>>(x, W, dinv, gq);
    scatter_kernel <<<dim3(NB, KPB), 256, 0, stream>>>(packed, boffs, gq, accp);
    finalize_kernel<<<640, 256, 0, stream>>>(accp, gq, dinv, b, dsum);
    out_kernel     <<<1, 16, 0, stream>>>(dsum, out);
}

// Round 9
// 264.927 us; speedup vs baseline: 1.5615x; 1.0877x over previous
//
#include <hip/hip_runtime.h>
#include <math.h>

#define N_NODES 100000
#define N_EDGES 6400000
#define F_IN 128
#define F_OUT 16
#define NB 391                 // ceil(100000/256) buckets of 256 target nodes
#define NBLK 1600              // chunks
#define EPB 4000               // edges per chunk: 1600 * 4000 = 6.4M exactly
#define LOCW 392               // loc row width
#define KPB 4                  // scatter blocks per bucket (1564 blocks, ~6.1/CU co-resident)
#define ACCN (NB * 256 * F_OUT)
#define QSCALE 1024.0f         // 2^10 fixed-point scale for the int16 gather table
#define QINV   (1.0f / 1024.0f)
#define FIN_GRID 640

// -------- 1. per-chunk per-bucket counts; also zeros the deg array --------
__global__ void __launch_bounds__(256) count_kernel(const int* __restrict__ col,
                                                    int* __restrict__ loc,
                                                    int* __restrict__ deg) {
    __shared__ int hist[NB];
    const int t = threadIdx.x, k = blockIdx.x;
    const int z0 = k * 63;                       // 1600*63 >= 100000
    for (int j = t; j < 63; j += 256)
        if (z0 + j < N_NODES) deg[z0 + j] = 0;
    for (int i = t; i < NB; i += 256) hist[i] = 0;
    __syncthreads();
    const int e0 = k * EPB;
    for (int i = t; i < EPB; i += 256) atomicAdd(&hist[col[e0 + i] >> 8], 1);
    __syncthreads();
    for (int b = t; b < NB; b += 256) loc[k * LOCW + b] = hist[b];
}

// -------- 2a. per-bucket exclusive prefix over chunks + bucket totals --------
__global__ void __launch_bounds__(256) desta_kernel(const int* __restrict__ loc,
        int* __restrict__ destT, int* __restrict__ total) {
    __shared__ int tsum[256];
    const int t = threadIdx.x, b = blockIdx.x;
    int v[7]; int s = 0;
    #pragma unroll
    for (int j = 0; j < 7; j++) {
        int k = t * 7 + j;
        v[j] = (k < NBLK) ? loc[k * LOCW + b] : 0;
        s += v[j];
    }
    tsum[t] = s;
    __syncthreads();
    for (int off = 1; off < 256; off <<= 1) {
        int a = (t >= off) ? tsum[t - off] : 0;
        __syncthreads();
        tsum[t] += a;
        __syncthreads();
    }
    int run = tsum[t] - s;   // exclusive prefix
    #pragma unroll
    for (int j = 0; j < 7; j++) {
        int k = t * 7 + j;
        if (k < NBLK) destT[(size_t)b * NBLK + k] = run;
        run += v[j];
    }
    if (t == 255) total[b] = tsum[255];
}

// -------- 2b. exclusive scan of bucket totals -> boffs --------
__global__ void destb_kernel(const int* __restrict__ total, int* __restrict__ boffs) {
    __shared__ int lds[512];
    const int t = threadIdx.x;
    int v = (t < NB) ? total[t] : 0;
    lds[t] = v; __syncthreads();
    for (int off = 1; off < 512; off <<= 1) {
        int a = (t >= off) ? lds[t - off] : 0; __syncthreads();
        lds[t] += a; __syncthreads();
    }
    if (t < NB) boffs[t] = lds[t] - v;
    if (t == NB) boffs[NB] = N_EDGES;
}

// -------- 3. place: LDS counting-sort each chunk, flush segments DIRECTLY to
//            bucket-contiguous global positions. --------
__global__ void __launch_bounds__(256) place_kernel(const int* __restrict__ row,
        const int* __restrict__ col, const int* __restrict__ destT,
        const int* __restrict__ boffs, unsigned int* __restrict__ packed) {
    __shared__ int hist[NB];
    __shared__ int scanb[512];
    __shared__ int base[NB];
    __shared__ int gadj[NB];
    __shared__ unsigned int tile[EPB];      // 16 KB
    __shared__ unsigned short tileb[EPB];   // 8 KB (bucket id per slot)
    const int t = threadIdx.x, k = blockIdx.x;
    const int e0 = k * EPB;
    int myc[16], myr[16];
    #pragma unroll
    for (int j = 0; j < 16; j++) {
        int idx = t + j * 256;
        if (idx < EPB) { myc[j] = col[e0 + idx]; myr[j] = row[e0 + idx]; }
        else { myc[j] = -1; myr[j] = 0; }
    }
    for (int i = t; i < NB; i += 256) hist[i] = 0;
    __syncthreads();
    #pragma unroll
    for (int j = 0; j < 16; j++)
        if (myc[j] >= 0) atomicAdd(&hist[myc[j] >> 8], 1);
    __syncthreads();
    scanb[t] = (t < NB) ? hist[t] : 0;
    scanb[t + 256] = (t + 256 < NB) ? hist[t + 256] : 0;
    __syncthreads();
    for (int off = 1; off < 512; off <<= 1) {
        int a  = (t >= off) ? scanb[t - off] : 0;
        int a2 = scanb[t + 256 - off];
        __syncthreads();
        scanb[t] += a; scanb[t + 256] += a2;
        __syncthreads();
    }
    if (t < NB) base[t] = scanb[t] - hist[t];
    if (t + 256 < NB) base[t + 256] = scanb[t + 256] - hist[t + 256];
    __syncthreads();
    for (int bb = t; bb < NB; bb += 256) {
        gadj[bb] = boffs[bb] + destT[(size_t)bb * NBLK + k] - base[bb];
        hist[bb] = 0;   // reuse as cursor
    }
    __syncthreads();
    #pragma unroll
    for (int j = 0; j < 16; j++) {
        if (myc[j] >= 0) {
            int bb = myc[j] >> 8;
            int pos = base[bb] + atomicAdd(&hist[bb], 1);     // native ds_add_rtn
            tile[pos] = ((unsigned)myr[j] << 8) | (unsigned)(myc[j] & 255);
            tileb[pos] = (unsigned short)bb;
        }
    }
    __syncthreads();
    for (int i = t; i < EPB; i += 256)
        packed[gadj[tileb[i]] + i] = tile[i];   // segment-contiguous global writes
}

// -------- 4. per-bucket degree, 4 slices per bucket, global int merge --------
__global__ void __launch_bounds__(256) deg_kernel(const unsigned int* __restrict__ packed,
        const int* __restrict__ boffs, int* __restrict__ deg) {
    __shared__ int dh[256];
    const int t = threadIdx.x;
    dh[t] = 0;
    __syncthreads();
    const int b = blockIdx.x, part = blockIdx.y;
    const int s = boffs[b], e = boffs[b + 1];
    const int chunk = (e - s + 3) >> 2;
    const int cs = s + part * chunk;
    const int ce = min(cs + chunk, e);
    for (int i = cs + t; i < ce; i += 256)
        atomicAdd(&dh[packed[i] & 255u], 1);
    __syncthreads();
    const int node = (b << 8) + t;
    if (node < N_NODES && dh[t]) atomicAdd(&deg[node], dh[t]);
}

// -------- 5. gq[n,f] = int16( rsqrt(deg+1) * (x@W)[n,f] * 2^10 ) --------
__global__ void __launch_bounds__(256) gemm_kernel(const float* __restrict__ x,
        const float* __restrict__ W, const int* __restrict__ deg,
        short* __restrict__ gq) {
    __shared__ float Ws[F_IN * F_OUT];        // 8 KB
    __shared__ float xs[16 * 132];            // stride 132: float4-aligned + conflict-free
    const int tid = threadIdx.x;
    const int n0 = blockIdx.x * 16;
    const float4* W4 = (const float4*)W;
    for (int i = tid; i < 512; i += 256) ((float4*)Ws)[i] = W4[i];
    const float4* x4 = (const float4*)(x + (size_t)n0 * F_IN);   // 16 rows x 32 float4
    for (int i = tid; i < 512; i += 256) {
        int n = i >> 5, j = i & 31;
        *(float4*)(xs + n * 132 + j * 4) = x4[i];
    }
    __syncthreads();
    const int node = tid >> 4, f = tid & 15;
    const float* xr = &xs[node * 132];
    float acc = 0.f;
    #pragma unroll 8
    for (int k = 0; k < F_IN; k++) acc += xr[k] * Ws[k * 16 + f];
    const float dinvn = rsqrtf((float)deg[n0 + node] + 1.0f);    // +1 self loop
    float v = acc * dinvn * QSCALE;
    v = fminf(fmaxf(v, -32000.f), 32000.f);
    gq[n0 * 16 + tid] = (short)__float2int_rn(v);
}

// -------- 6. dense scatter: int16 gather (3.2 MB L2-resident) -> ds_add.
//            KPB=4 slices, 256-thr blocks, all co-resident. --------
__global__ void __launch_bounds__(256) scatter_kernel(
        const unsigned int* __restrict__ packed, const int* __restrict__ boffs,
        const short* __restrict__ gq, int* __restrict__ accp) {
    __shared__ int sacc[256 * F_OUT];   // 16 KB
    const int t = threadIdx.x;
    for (int i = t; i < 256 * F_OUT; i += 256) sacc[i] = 0;
    __syncthreads();
    const int b = blockIdx.x, part = blockIdx.y;
    const int s = boffs[b], e = boffs[b + 1];
    const int chunk = (e - s + KPB - 1) / KPB;
    const int cs = s + part * chunk;
    const int ce = min(cs + chunk, e);
    const int f = t & 15, eg = t >> 4;    // 16 edges per step
    int i = cs + eg;
    for (; i + 48 < ce; i += 64) {        // 4x unroll: 4 gathers in flight
        unsigned p0 = packed[i];
        unsigned p1 = packed[i + 16];
        unsigned p2 = packed[i + 32];
        unsigned p3 = packed[i + 48];
        int v0 = gq[(p0 >> 8) * 16 + f];
        int v1 = gq[(p1 >> 8) * 16 + f];
        int v2 = gq[(p2 >> 8) * 16 + f];
        int v3 = gq[(p3 >> 8) * 16 + f];
        atomicAdd(&sacc[((p0 & 255u) << 4) + f], v0);
        atomicAdd(&sacc[((p1 & 255u) << 4) + f], v1);
        atomicAdd(&sacc[((p2 & 255u) << 4) + f], v2);
        atomicAdd(&sacc[((p3 & 255u) << 4) + f], v3);
    }
    for (; i < ce; i += 16) {
        unsigned p0 = packed[i];
        atomicAdd(&sacc[((p0 & 255u) << 4) + f], (int)gq[(p0 >> 8) * 16 + f]);
    }
    __syncthreads();
    const int nbase = b << 8;
    int* dst = accp + (size_t)part * ACCN + ((size_t)nbase << 4);
    for (int j = t; j < 256 * F_OUT; j += 256)
        if (nbase + (j >> 4) < N_NODES) dst[j] = sacc[j];
}

// -------- 7. out_n = tanh(dinv[n]*(acc+g) + b); mean; fused final output --------
__global__ void __launch_bounds__(256) finalize_kernel(const int* __restrict__ accp,
        const short* __restrict__ gq, const int* __restrict__ deg,
        const float* __restrict__ b, double* __restrict__ dsum,
        int* __restrict__ done, float* __restrict__ out) {
    __shared__ float s[4][16];
    __shared__ int lastflag;
    const int tid = threadIdx.x;
    const int f = tid & 15;
    const float bf = b[f];
    float local = 0.f;
    for (int i = blockIdx.x * blockDim.x + tid; i < N_NODES * F_OUT;
         i += gridDim.x * blockDim.x) {
        const int n = i >> 4;
        int ai = accp[i] + accp[ACCN + i] + accp[2 * ACCN + i] + accp[3 * ACCN + i]
               + (int)gq[i];
        float dinvn = rsqrtf((float)deg[n] + 1.0f);
        local += tanhf(dinvn * ((float)ai * QINV) + bf);
    }
    local += __shfl_down(local, 32);
    local += __shfl_down(local, 16);
    const int lane = tid & 63, wave = tid >> 6;
    if (lane < 16) s[wave][lane] = local;
    __syncthreads();
    if (tid < 16) {
        float v = s[0][tid] + s[1][tid] + s[2][tid] + s[3][tid];
        atomicAdd(&dsum[tid], (double)v);
    }
    if (tid == 0) {
        __threadfence();   // wave 0's dsum atomics drained to coherent point
        lastflag = (atomicAdd(done, 1) == (int)gridDim.x - 1);
    }
    __syncthreads();
    if (lastflag && tid < 16) {
        double v = atomicAdd(&dsum[tid], 0.0);   // coherent read
        out[tid] = (float)(v * (1.0 / (double)N_NODES));
    }
}

extern "C" void kernel_launch(void* const* d_in, const int* in_sizes, int n_in,
                              void* d_out, int out_size, void* d_ws, size_t ws_size,
                              hipStream_t stream) {
    const float* x  = (const float*)d_in[0];
    const int*   ei = (const int*)d_in[1];
    const float* W  = (const float*)d_in[2];
    const float* b  = (const float*)d_in[3];
    float* out = (float*)d_out;

    const int* row = ei;             // edge_index[0] = source
    const int* col = ei + N_EDGES;   // edge_index[1] = target

    // workspace layout (~54.9 MB); loc+destT overlaid with accp (disjoint lifetimes):
    char* p = (char*)d_ws;
    double*       dsum   = (double*)p;        p += 16 * 8;
    int*          done   = (int*)p;           p += 16;
    int*          total  = (int*)p;           p += 1568;
    int*          boffs  = (int*)p;           p += (NB + 1) * 4;    // 1568
    int*          deg    = (int*)p;           p += (size_t)N_NODES * 4;        // 0.4 MB
    short*        gq     = (short*)p;         p += (size_t)N_NODES * F_OUT * 2; // 3.2 MB
    unsigned int* packed = (unsigned int*)p;  p += (size_t)N_EDGES * 4;        // 25.6 MB
    char*         shared = p;                 // max(loc+destT, accp) = 25.6 MB
    int*          loc    = (int*)shared;                               // 2.5 MB
    int*          destT  = (int*)(shared + (size_t)NBLK * LOCW * 4);   // 2.5 MB
    int*          accp   = (int*)shared;                               // KPB*ACCN i32

    hipMemsetAsync(dsum, 0, 16 * 8 + 16, stream);   // dsum + done

    count_kernel   <<<NBLK, 256, 0, stream>>>(col, loc, deg);
    desta_kernel   <<<NB, 256, 0, stream>>>(loc, destT, total);
    destb_kernel   <<<1, 512, 0, stream>>>(total, boffs);
    place_kernel   <<<NBLK, 256, 0, stream>>>(row, col, destT, boffs, packed);
    deg_kernel     <<<dim3(NB, 4), 256, 0, stream>>>(packed, boffs, deg);
    gemm_kernel    <<<N_NODES / 16, 256, 0, stream>>>(x, W, deg, gq);
    scatter_kernel <<<dim3(NB, KPB), 256, 0, stream>>>(packed, boffs, gq, accp);
    finalize_kernel<<<FIN_GRID, 256, 0, stream>>>(accp, gq, deg, b, dsum, done, out);
}